// Round 3
// baseline (342.088 us; speedup 1.0000x reference)
//
#include <hip/hip_runtime.h>
#include <hip/hip_bf16.h>

#define LMAXV 8
#define NCOL 81                  // (LMAX+1)^2
#define ROWB 324                 // bytes per output row (81 * 4, float32)
#define WAVESZ 64
#define WPB 2                    // waves per block
#define BLOCKSZ 128
#define BCHUNK (BLOCKSZ * ROWB)  // 41472 bytes per block, 16B-aligned, < 64 KiB

// ---------- compile-time associated-Legendre coefficient table ----------
struct LMCoef { float c[5]; int T; int par; };

constexpr double cfact(int n) { double r = 1.0; for (int i = 2; i <= n; ++i) r *= (double)i; return r; }
constexpr double ccomb(int n, int k) { return cfact(n) / (cfact(k) * cfact(n - k)); }
constexpr double csqrt_(double x) { double g = x > 1.0 ? x : 1.0; for (int i = 0; i < 200; ++i) g = 0.5 * (g + x / g); return g; }
constexpr double CPI_ = 3.14159265358979323846;

// P_{l,m}(z,y) = norm * y^m * d^{l+m}/dz^{l+m} (z^2-1)^l
// expressed as z^par * sum_j c[j] * (z^2)^j  (the y^m factor applied at runtime)
constexpr LMCoef make_lm(int l, int m) {
  LMCoef r{{0.f, 0.f, 0.f, 0.f, 0.f}, 0, 0};
  const int n = l + m;
  const double norm = csqrt_((double)(2 * l + 1) / (4.0 * CPI_) * cfact(l - m) / cfact(l + m))
                      / ((double)(1 << l) * cfact(l));
  r.par = (l - m) & 1;
  r.T = (l - m) / 2 + 1;
  for (int j = 0; j < r.T; ++j) {
    const int p = 2 * j + r.par + n;   // p = 2k: power of z inside (z^2-1)^l expansion
    const int k = p / 2;
    const double c = ccomb(l, k) * (((l - k) & 1) ? -1.0 : 1.0) * (cfact(p) / cfact(p - n));
    r.c[j] = (float)(norm * c);
  }
  return r;
}

constexpr LMCoef G_LM[45] = {
  make_lm(0,0),
  make_lm(1,0), make_lm(1,1),
  make_lm(2,0), make_lm(2,1), make_lm(2,2),
  make_lm(3,0), make_lm(3,1), make_lm(3,2), make_lm(3,3),
  make_lm(4,0), make_lm(4,1), make_lm(4,2), make_lm(4,3), make_lm(4,4),
  make_lm(5,0), make_lm(5,1), make_lm(5,2), make_lm(5,3), make_lm(5,4), make_lm(5,5),
  make_lm(6,0), make_lm(6,1), make_lm(6,2), make_lm(6,3), make_lm(6,4), make_lm(6,5), make_lm(6,6),
  make_lm(7,0), make_lm(7,1), make_lm(7,2), make_lm(7,3), make_lm(7,4), make_lm(7,5), make_lm(7,6), make_lm(7,7),
  make_lm(8,0), make_lm(8,1), make_lm(8,2), make_lm(8,3), make_lm(8,4), make_lm(8,5), make_lm(8,6), make_lm(8,7), make_lm(8,8)
};

// ------------------------------ kernel ------------------------------
__global__ __launch_bounds__(BLOCKSZ) void sh_ab_kernel(
    const float* __restrict__ alpha,
    const float* __restrict__ beta,
    float* __restrict__ out, int n)
{
  __shared__ uint4 ldsbuf[BCHUNK / 16];
  float* lds = (float*)ldsbuf;

  const int tid = blockIdx.x * BLOCKSZ + threadIdx.x;

  float a = 0.f, b = 0.f;
  if (tid < n) {
    a = alpha[tid];               // float32 inputs
    b = beta[tid];
  }
  float sa, ca, sb, cbeta;
  __sincosf(a, &sa, &ca);
  __sincosf(b, &sb, &cbeta);
  const float z = cbeta, y = sb;
  const float z2 = z * z;

  // S[m] = sqrt2*sin(m*alpha), C[m] = sqrt2*cos(m*alpha)  (sqrt2 folded into seed)
  float S[LMAXV + 1], C[LMAXV + 1];
  S[1] = 1.41421356237309505f * sa;
  C[1] = 1.41421356237309505f * ca;
#pragma unroll
  for (int m = 2; m <= LMAXV; ++m) {
    C[m] = C[m - 1] * ca - S[m - 1] * sa;
    S[m] = S[m - 1] * ca + C[m - 1] * sa;
  }

  float YM[LMAXV + 1], ZYM[LMAXV + 1];
  YM[0] = 1.f;
#pragma unroll
  for (int m = 1; m <= LMAXV; ++m) YM[m] = YM[m - 1] * y;
#pragma unroll
  for (int m = 0; m <= LMAXV; ++m) ZYM[m] = z * YM[m];

  // per-thread row in LDS: stride 81 floats (odd stride -> conflict-free)
  float* myrow = lds + threadIdx.x * NCOL;

#pragma unroll
  for (int l = 0; l <= LMAXV; ++l) {
    float leg[LMAXV + 1];
#pragma unroll
    for (int mm = 0; mm <= l; ++mm) {
      const int idx = l * (l + 1) / 2 + mm;
      float v = 0.f;
#pragma unroll
      for (int j = 4; j >= 0; --j) {
        if (j < G_LM[idx].T) v = v * z2 + G_LM[idx].c[j];
      }
      leg[mm] = v * (G_LM[idx].par ? ZYM[mm] : YM[mm]);
    }
    const int colbase = l * l;
    // m = -l .. -1  -> sqrt2*sin(|m| a), descending |m|
#pragma unroll
    for (int j = 0; j < l; ++j) {
      myrow[colbase + j] = leg[l - j] * S[l - j];
    }
    // m = 0
    myrow[colbase + l] = leg[0];
    // m = 1 .. l -> sqrt2*cos(m a)
#pragma unroll
    for (int j = 1; j <= l; ++j) {
      myrow[colbase + l + j] = leg[j] * C[j];
    }
  }

  __syncthreads();

  // Block-cooperative coalesced copy-out: 41472 B = 2592 uint4
  const long blockByteBase = (long)blockIdx.x * BCHUNK;
  const long limitBytes = (long)n * ROWB - blockByteBase;
  uint4* gdst = (uint4*)((char*)out + blockByteBase);
  const uint4* lsrc = (const uint4*)lds;
  for (int o = threadIdx.x; o < BCHUNK / 16; o += BLOCKSZ) {
    if ((long)o * 16 < limitBytes) gdst[o] = lsrc[o];
  }
}

// ------------------------------ launch ------------------------------
extern "C" void kernel_launch(void* const* d_in, const int* in_sizes, int n_in,
                              void* d_out, int out_size, void* d_ws, size_t ws_size,
                              hipStream_t stream) {
  const float* alpha = (const float*)d_in[0];
  const float* beta  = (const float*)d_in[1];
  float* out = (float*)d_out;
  const int n = in_sizes[0];
  const int grid = (n + BLOCKSZ - 1) / BLOCKSZ;
  hipLaunchKernelGGL(sh_ab_kernel, dim3(grid), dim3(BLOCKSZ), 0, stream,
                     alpha, beta, out, n);
}